// Round 1
// 568.915 us; speedup vs baseline: 1.3428x; 1.3428x over previous
//
#include <hip/hip_runtime.h>
#include <hip/hip_bf16.h>
#include <cstdint>

#define NV 3
#define NN 4096
#define HH 256
#define CC 20
#define DYY 300
#define DD 512

typedef __bf16 v8bf  __attribute__((ext_vector_type(8)));
typedef float  v16f  __attribute__((ext_vector_type(16)));

static __device__ __forceinline__ float bf2f(unsigned short u) {
    union { unsigned int i; float f; } c; c.i = ((unsigned int)u) << 16; return c.f;
}

// Stage a 128x64 bf16 tile (rows r0..r0+127, cols k0..k0+63 of a row-major
// source with row stride strideElems) into a 16 KB LDS buffer via
// global_load_lds width=16. LDS dest is linear (HW requirement, m104);
// the XOR swizzle (chunk ^= row&7) is applied on the GLOBAL source side
// (rule #21), and the matching XOR is applied on ds_read. This puts the
// 64-lane ds_read_b128 MFMA-fragment read at the 8-cycle structural floor
// instead of a 32-way bank conflict (rows are 128 B = exactly 32 banks).
static __device__ __forceinline__ void stage_tile(const __bf16* src, int strideElems,
                                                  char* lds, int tid)
{
#pragma unroll
    for (int i = 0; i < 4; ++i) {
        int id = i * 256 + tid;          // 16 B chunk id, 0..1023
        int r = id >> 3, c = id & 7;
        const char* g = (const char*)(src + (size_t)r * strideElems)
                        + ((c ^ (r & 7)) << 4);
        __builtin_amdgcn_global_load_lds(
            (const __attribute__((address_space(1))) unsigned int*)g,
            (__attribute__((address_space(3))) unsigned int*)(lds + id * 16),
            16, 0, 0);
    }
}

// swizzled fragment read: row ra (0..127), 16B-chunk q (0..7) of that row
static __device__ __forceinline__ v8bf frag_read(const char* lds, int ra, int q)
{
    return *(const v8bf*)(lds + ra * 128 + ((q ^ (ra & 7)) << 4));
}

// ---------------------------------------------------------------- k_yn
__global__ __launch_bounds__(256) void k_yn(
    const float* __restrict__ y, const float* __restrict__ Wy,
    const float* __restrict__ by, float* __restrict__ YN)
{
    __shared__ float ysh[DYY];
    int c = blockIdx.x, tid = threadIdx.x;
    for (int i = tid; i < DYY; i += 256) ysh[i] = y[c * DYY + i];
    __syncthreads();
    float acc = by[tid];
    const float* Wr = Wy + (size_t)tid * DYY;
    for (int d = 0; d < DYY; ++d) acc += ysh[d] * Wr[d];
    YN[c * HH + tid] = 1.0f / (1.0f + __expf(-acc));
}

// ---------------------------------------------------------------- k_proj
__global__ __launch_bounds__(256) void k_proj(
    const float* __restrict__ x0, const float* __restrict__ x1, const float* __restrict__ x2,
    const float* __restrict__ W0, const float* __restrict__ W1, const float* __restrict__ W2,
    const float* __restrict__ b0, const float* __restrict__ b1, const float* __restrict__ b2,
    const int* __restrict__ mask,
    float* __restrict__ XP, __hip_bfloat16* __restrict__ XQh,
    __hip_bfloat16* __restrict__ XPMT)
{
    const int R = 8;
    int tid = threadIdx.x;
    int blk = blockIdx.x;
    int v  = blk / (NN / R);
    int n0 = (blk % (NN / R)) * R;
    const float* xv = (v == 0) ? x0 : (v == 1 ? x1 : x2);
    const float* Wv = (v == 0) ? W0 : (v == 1 ? W1 : W2);
    const float* bv = (v == 0) ? b0 : (v == 1 ? b1 : b2);

    __shared__ __align__(16) float xsh[R][DD];
    __shared__ float wred[4][R];
    __shared__ float nrm_sh[R];
    __shared__ int   msk_sh[R];

    const float4* xsrc = (const float4*)(xv + (size_t)n0 * DD);
    for (int i = tid; i < R * DD / 4; i += 256)
        ((float4*)xsh)[i] = xsrc[i];
    if (tid < R) msk_sh[tid] = mask[(n0 + tid) * NV + v];
    __syncthreads();

    float acc[R];
#pragma unroll
    for (int r = 0; r < R; ++r) acc[r] = 0.0f;
    const float4* Wrow = (const float4*)(Wv + (size_t)tid * DD);
    for (int d4 = 0; d4 < DD / 4; ++d4) {
        float4 w = Wrow[d4];
#pragma unroll
        for (int r = 0; r < R; ++r) {
            acc[r] = fmaf(xsh[r][4 * d4 + 0], w.x, acc[r]);
            acc[r] = fmaf(xsh[r][4 * d4 + 1], w.y, acc[r]);
            acc[r] = fmaf(xsh[r][4 * d4 + 2], w.z, acc[r]);
            acc[r] = fmaf(xsh[r][4 * d4 + 3], w.w, acc[r]);
        }
    }
    float bb = bv[tid];
    float vals[R];
#pragma unroll
    for (int r = 0; r < R; ++r) {
        float t = acc[r] + bb;
        vals[r] = (t >= 0.0f) ? t : 0.1f * t;
    }
    int lane = tid & 63, wv = tid >> 6;
#pragma unroll
    for (int r = 0; r < R; ++r) {
        float sq = vals[r] * vals[r];
#pragma unroll
        for (int off = 32; off > 0; off >>= 1)
            sq += __shfl_down(sq, off, 64);
        if (lane == 0) wred[wv][r] = sq;
    }
    __syncthreads();
    if (tid < R) {
        float s = wred[0][tid] + wred[1][tid] + wred[2][tid] + wred[3][tid];
        nrm_sh[tid] = fmaxf(sqrtf(s), 1e-12f);
    }
    __syncthreads();
    union { __hip_bfloat16 h[8]; uint4 u; } pk;
#pragma unroll
    for (int r = 0; r < R; ++r) {
        size_t o = ((size_t)v * NN + n0 + r) * HH + tid;
        float xpv = vals[r];
        XP[o]  = xpv;
        XQh[o] = __float2bfloat16(xpv / nrm_sh[r]);
        pk.h[r] = __float2bfloat16(msk_sh[r] ? xpv : 0.0f);
    }
    *(uint4*)&XPMT[((size_t)v * HH + tid) * NN + n0] = pk.u;
}

// ---------------------------------------------------------------- k_scores
// Symmetric: S[n][m] == S[m][n]. Compute only upper-triangular 128x128 tiles
// (528 of 1024 blocks), mirror-write the transpose for off-diagonal tiles.
// Per block: 4 waves, each a 64x64 wave-tile (2x2 of 32x32 MFMA).
// v looped sequentially; comb keeps max over v of the mask-GATED DOT
// (-1e30 when gated out); one expf at the end (exp is monotonic).
__global__ __launch_bounds__(256) void k_scores(
    const __hip_bfloat16* __restrict__ XQh, const int* __restrict__ mask,
    __hip_bfloat16* __restrict__ Sb)
{
    // triangular decode: blockIdx.x -> (bi, bj), bi <= bj
    const int T = NN / 128;                 // 32
    int rem = blockIdx.x, bi = 0;
    while (rem >= T - bi) { rem -= T - bi; ++bi; }
    int bj = bi + rem;
    int n0 = bi * 128, m0 = bj * 128;

    int tid = threadIdx.x, lane = tid & 63, wid = tid >> 6;
    int wr = (wid >> 1) * 64, wc = (wid & 1) * 64;
    int rowA = lane & 31, hi = lane >> 5;

    __shared__ __align__(128) char Ash[16384];
    __shared__ __align__(128) char Bsh[16384];
    __shared__ int mnsh[NV][128], mmsh[NV][128];

    if (tid < 128) {
#pragma unroll
        for (int v = 0; v < NV; ++v) {
            mnsh[v][tid] = mask[(n0 + tid) * NV + v];
            mmsh[v][tid] = mask[(m0 + tid) * NV + v];
        }
    }

    float comb[2][2][16];
#pragma unroll
    for (int i = 0; i < 2; ++i)
#pragma unroll
        for (int j = 0; j < 2; ++j)
#pragma unroll
            for (int r = 0; r < 16; ++r) comb[i][j][r] = -1e30f;

#pragma unroll 1
    for (int v = 0; v < NV; ++v) {
        v16f acc[2][2];
#pragma unroll
        for (int i = 0; i < 2; ++i)
#pragma unroll
            for (int j = 0; j < 2; ++j) acc[i][j] = (v16f)0.0f;

        const __bf16* Apanel = (const __bf16*)XQh + ((size_t)v * NN + n0) * HH;
        const __bf16* Bpanel = (const __bf16*)XQh + ((size_t)v * NN + m0) * HH;

#pragma unroll 1
        for (int k0 = 0; k0 < HH; k0 += 64) {
            __syncthreads();                     // protect LDS from prev readers
            stage_tile(Apanel + k0, HH, Ash, tid);
            stage_tile(Bpanel + k0, HH, Bsh, tid);
            __syncthreads();                     // vmcnt(0) drain + barrier
#pragma unroll
            for (int kk = 0; kk < 4; ++kk) {
                int q = kk * 2 + hi;
                v8bf af[2], bfr[2];
#pragma unroll
                for (int t = 0; t < 2; ++t) {
                    af[t]  = frag_read(Ash, wr + t * 32 + rowA, q);
                    bfr[t] = frag_read(Bsh, wc + t * 32 + rowA, q);
                }
#pragma unroll
                for (int i = 0; i < 2; ++i)
#pragma unroll
                    for (int j = 0; j < 2; ++j)
                        acc[i][j] = __builtin_amdgcn_mfma_f32_32x32x16_bf16(
                            af[i], bfr[j], acc[i][j], 0, 0, 0);
            }
        }

        // fold gated dot into running max
#pragma unroll
        for (int i = 0; i < 2; ++i)
#pragma unroll
            for (int j = 0; j < 2; ++j) {
                int cm = mmsh[v][wc + j * 32 + rowA];
#pragma unroll
                for (int r = 0; r < 16; ++r) {
                    int rown = wr + i * 32 + (r & 3) + 8 * (r >> 2) + 4 * hi;
                    float g = (cm && mnsh[v][rown]) ? acc[i][j][r] : -1e30f;
                    comb[i][j][r] = fmaxf(comb[i][j][r], g);
                }
            }
    }

    // epilogue: exp + diag-zero, forward write, mirror write (transposed)
#pragma unroll
    for (int i = 0; i < 2; ++i)
#pragma unroll
        for (int j = 0; j < 2; ++j) {
            int m = m0 + wc + j * 32 + rowA;
            float sv[16];
#pragma unroll
            for (int r = 0; r < 16; ++r) {
                int rown = wr + i * 32 + (r & 3) + 8 * (r >> 2) + 4 * hi;
                float e = __expf(comb[i][j][r] * 5.0f);   // exp(-5e30)->0 when all-masked
                if (n0 + rown == m) e = 0.0f;
                sv[r] = e;
                Sb[(size_t)(n0 + rown) * NN + m] = __float2bfloat16(e);
            }
            if (bi != bj) {
#pragma unroll
                for (int g4 = 0; g4 < 4; ++g4) {
                    union { __hip_bfloat16 h[4]; uint2 u; } pk;
#pragma unroll
                    for (int j2 = 0; j2 < 4; ++j2)
                        pk.h[j2] = __float2bfloat16(sv[4 * g4 + j2]);
                    int nbase = n0 + wr + i * 32 + 8 * g4 + 4 * hi;
                    *(uint2*)((unsigned short*)Sb + (size_t)m * NN + nbase) = pk.u;
                }
            }
        }
}

// ---------------------------------------------------------------- k_rowstats
__global__ __launch_bounds__(256) void k_rowstats(
    const __hip_bfloat16* __restrict__ Sb, const int* __restrict__ mask,
    float* __restrict__ RS, float* __restrict__ CONF)
{
    int n = blockIdx.x, tid = threadIdx.x;
    float lsum = 0.0f;
    float lm[NV] = {-1e30f, -1e30f, -1e30f};
    const ushort4* S4 = (const ushort4*)(Sb + (size_t)n * NN);
    for (int i = tid; i < NN / 4; i += 256) {
        ushort4 u = S4[i];
        float f[4] = {bf2f(u.x), bf2f(u.y), bf2f(u.z), bf2f(u.w)};
        int mbase = (i * 4) * NV;
#pragma unroll
        for (int j = 0; j < 4; ++j) {
            lsum += f[j];
            float lg = 0.2f * __logf(f[j] + 1e-9f);
#pragma unroll
            for (int v = 0; v < NV; ++v) {
                float term = mask[mbase + j * NV + v] ? lg : 0.0f;
                lm[v] = fmaxf(lm[v], term);
            }
        }
    }
    int lane = tid & 63, wv = tid >> 6;
    __shared__ float ssum[4];
    __shared__ float smax[4][NV];
#pragma unroll
    for (int off = 32; off > 0; off >>= 1) {
        lsum += __shfl_down(lsum, off, 64);
#pragma unroll
        for (int v = 0; v < NV; ++v)
            lm[v] = fmaxf(lm[v], __shfl_down(lm[v], off, 64));
    }
    if (lane == 0) {
        ssum[wv] = lsum;
#pragma unroll
        for (int v = 0; v < NV; ++v) smax[wv][v] = lm[v];
    }
    __syncthreads();
    if (tid == 0) RS[n] = ssum[0] + ssum[1] + ssum[2] + ssum[3];
    if (tid < NV) {
        float cm = fmaxf(fmaxf(smax[0][tid], smax[1][tid]),
                         fmaxf(smax[2][tid], smax[3][tid]));
        CONF[tid * NN + n] = fminf(fmaxf(cm, 0.0f), 1.0f);
    }
}

// ---------------------------------------------------------------- k_newx
// Same LDS-staged structure: 128x128 tile, 4 waves x 64x64, K=4096, BK=64.
// grid (NN/128, HH/128, NV) = (32, 2, 3).
__global__ __launch_bounds__(256) void k_newx(
    const __hip_bfloat16* __restrict__ Sb, const __hip_bfloat16* __restrict__ XPMT,
    const float* __restrict__ XP, const float* __restrict__ RS,
    const int* __restrict__ mask, float* __restrict__ NX)
{
    int v  = blockIdx.z;
    int n0 = blockIdx.x * 128, h0 = blockIdx.y * 128;
    int tid = threadIdx.x, lane = tid & 63, wid = tid >> 6;
    int wr = (wid >> 1) * 64, wc = (wid & 1) * 64;
    int rowA = lane & 31, hi = lane >> 5;

    __shared__ __align__(128) char Ash[16384];
    __shared__ __align__(128) char Bsh[16384];
    __shared__ int   mn[128];
    __shared__ float rsn[128];
    if (tid < 128) {
        mn[tid]  = mask[(n0 + tid) * NV + v];
        rsn[tid] = 1.0f / (RS[n0 + tid] + 1e-9f);
    }

    v16f acc[2][2];
#pragma unroll
    for (int i = 0; i < 2; ++i)
#pragma unroll
        for (int j = 0; j < 2; ++j) acc[i][j] = (v16f)0.0f;

    const __bf16* Apanel = (const __bf16*)Sb + (size_t)n0 * NN;
    const __bf16* Bpanel = (const __bf16*)XPMT + ((size_t)v * HH + h0) * NN;

#pragma unroll 1
    for (int k0 = 0; k0 < NN; k0 += 64) {
        __syncthreads();
        stage_tile(Apanel + k0, NN, Ash, tid);
        stage_tile(Bpanel + k0, NN, Bsh, tid);
        __syncthreads();
#pragma unroll
        for (int kk = 0; kk < 4; ++kk) {
            int q = kk * 2 + hi;
            v8bf af[2], bfr[2];
#pragma unroll
            for (int t = 0; t < 2; ++t) {
                af[t]  = frag_read(Ash, wr + t * 32 + rowA, q);
                bfr[t] = frag_read(Bsh, wc + t * 32 + rowA, q);
            }
#pragma unroll
            for (int i = 0; i < 2; ++i)
#pragma unroll
                for (int j = 0; j < 2; ++j)
                    acc[i][j] = __builtin_amdgcn_mfma_f32_32x32x16_bf16(
                        af[i], bfr[j], acc[i][j], 0, 0, 0);
        }
    }

#pragma unroll
    for (int i = 0; i < 2; ++i)
#pragma unroll
        for (int j = 0; j < 2; ++j) {
            int h = h0 + wc + j * 32 + rowA;
#pragma unroll
            for (int r = 0; r < 16; ++r) {
                int rown = wr + i * 32 + (r & 3) + 8 * (r >> 2) + 4 * hi;
                size_t o = ((size_t)v * NN + n0 + rown) * HH + h;
                NX[o] = mn[rown] ? XP[o] : acc[i][j][r] * rsn[rown];
            }
        }
}

// ---------------------------------------------------------------- k_z
__global__ __launch_bounds__(256) void k_z(
    const float* __restrict__ NX, const float* __restrict__ YN,
    float* __restrict__ Z)
{
    int blk = blockIdx.x;
    int tid = threadIdx.x;
    float nx = NX[(size_t)blk * HH + tid];
    size_t base = (size_t)blk * CC * HH;
#pragma unroll
    for (int c = 0; c < CC; ++c)
        Z[base + (size_t)c * HH + tid] = nx * YN[c * HH + tid];
}

// ---------------------------------------------------------------- launch
extern "C" void kernel_launch(void* const* d_in, const int* in_sizes, int n_in,
                              void* d_out, int out_size, void* d_ws, size_t ws_size,
                              hipStream_t stream)
{
    (void)in_sizes; (void)n_in; (void)out_size; (void)ws_size;
    const float* x0 = (const float*)d_in[0];
    const float* W0 = (const float*)d_in[1];
    const float* b0 = (const float*)d_in[2];
    const float* x1 = (const float*)d_in[3];
    const float* W1 = (const float*)d_in[4];
    const float* b1 = (const float*)d_in[5];
    const float* x2 = (const float*)d_in[6];
    const float* W2 = (const float*)d_in[7];
    const float* b2 = (const float*)d_in[8];
    const float* y  = (const float*)d_in[9];
    const float* Wy = (const float*)d_in[10];
    const float* by = (const float*)d_in[11];
    const int* mask = (const int*)d_in[12];
    float* out = (float*)d_out;

    __hip_bfloat16* Sb   = (__hip_bfloat16*)out;
    float*          XP   = out + 8388608;
    __hip_bfloat16* XQh  = (__hip_bfloat16*)(out + 11534336);
    __hip_bfloat16* XPMT = (__hip_bfloat16*)(out + 13107200);
    float*          CONF = out + (size_t)NV * NN * CC * HH;

    float* NX = (float*)d_ws;
    float* RS = NX + (size_t)NV * NN * HH;
    float* YN = RS + NN;

    k_yn<<<CC, 256, 0, stream>>>(y, Wy, by, YN);
    k_proj<<<NV * NN / 8, 256, 0, stream>>>(x0, x1, x2, W0, W1, W2,
                                            b0, b1, b2, mask, XP, XQh, XPMT);
    const int T = NN / 128;                       // 32
    k_scores<<<T * (T + 1) / 2, 256, 0, stream>>>(XQh, mask, Sb);
    k_rowstats<<<NN, 256, 0, stream>>>(Sb, mask, RS, CONF);
    dim3 gn(NN / 128, HH / 128, NV);
    k_newx<<<gn, 256, 0, stream>>>(Sb, XPMT, XP, RS, mask, NX);
    k_z<<<NV * NN, 256, 0, stream>>>(NX, YN, out);
}